// Round 1
// 1016.484 us; speedup vs baseline: 1.0131x; 1.0131x over previous
//
#include <hip/hip_runtime.h>

// RBF kernel, D=1 case: out[b,i,j] = exp(-(x1[b,i]-x2[b,j])^2 / (2*s^2)).
// Output = 4*8192*8192 fp32 = 1.07 GB -> pure HBM-write-bound (~175 us floor
// at 6.3 TB/s). Harness poison-fill (~688 us) is inside the timed region and
// is not ours to optimize; the kernel itself was ~342 us (= half of fill BW).
//
// This version vs previous:
//  - PLAIN stores, not __builtin_nontemporal_store. The harness fill proves
//    plain full-line wave stores (64 lanes x 16B = 1 KB contiguous) stream at
//    6.25 TB/s; the nt policy bit is the prime suspect for the exact-2x write
//    BW loss. x2 is 128 KB total, so L2 pollution (nt's only upside) is moot.
//  - ROWS=8 rows per block: each loaded x2 float4 feeds 8 output rows ->
//    8x less L2 read traffic, 8 independent 1KB wave-stores in flight per
//    load, fewer blocks (4096) with longer-lived store pipelines.
//  - __builtin_amdgcn_exp2f: raw v_exp_f32 (1 ulp, plenty for absmax 4e-3),
//    skipping OCML exp2f's denormal fixup ops.

#define THREADS 256
#define ROWS 8

typedef float vfloat4 __attribute__((ext_vector_type(4)));

template <int R>
__global__ __launch_bounds__(THREADS) void rbf_tile_kernel(
    const float* __restrict__ x1,
    const float* __restrict__ x2,
    const float* __restrict__ scale,
    float* __restrict__ out,
    int N1, int N2) {
  const int row0 = blockIdx.x * R;   // flat b*N1 + i; launch guarantees N1 % R == 0
  const int b    = row0 / N1;        // tile never straddles batch boundary
  const float s  = scale[0];
  // exp(-d^2/(2 s^2)) == exp2(c2 * d^2), c2 = -log2(e) / (2 s^2)
  const float c2 = -1.4426950408889634f / (2.0f * s * s);

  float a[R];
#pragma unroll
  for (int r = 0; r < R; ++r) a[r] = x1[row0 + r];   // wave-uniform broadcasts

  const vfloat4* __restrict__ x2v = (const vfloat4*)(x2 + (size_t)b * N2);
  float* const out0 = out + (size_t)row0 * N2;
  const int n4 = N2 >> 2;   // 2048 float4 per row

  for (int j4 = threadIdx.x; j4 < n4; j4 += THREADS) {
    const vfloat4 v = x2v[j4];   // one L2-hot load feeds R rows
#pragma unroll
    for (int r = 0; r < R; ++r) {
      vfloat4 d, e;
      d.x = a[r] - v.x;
      d.y = a[r] - v.y;
      d.z = a[r] - v.z;
      d.w = a[r] - v.w;
      e.x = __builtin_amdgcn_exp2f(c2 * d.x * d.x);
      e.y = __builtin_amdgcn_exp2f(c2 * d.y * d.y);
      e.z = __builtin_amdgcn_exp2f(c2 * d.z * d.z);
      e.w = __builtin_amdgcn_exp2f(c2 * d.w * d.w);
      // plain streaming store: full-line write-combine path (fill-speed)
      *(vfloat4*)(out0 + (size_t)r * N2 + ((size_t)j4 << 2)) = e;
    }
  }
}

extern "C" void kernel_launch(void* const* d_in, const int* in_sizes, int n_in,
                              void* d_out, int out_size, void* d_ws, size_t ws_size,
                              hipStream_t stream) {
  const float* x1    = (const float*)d_in[0];
  const float* x2    = (const float*)d_in[1];
  const float* scale = (const float*)d_in[2];
  float* out = (float*)d_out;

  const int B  = 4;                 // per reference setup_inputs()
  const int N1 = in_sizes[0] / B;   // 8192 (D=1)
  const int N2 = in_sizes[1] / B;   // 8192

  if ((N1 % ROWS) == 0) {
    dim3 grid((B * N1) / ROWS);     // 4096 blocks, 256 KB written per block
    rbf_tile_kernel<ROWS><<<grid, dim3(THREADS), 0, stream>>>(x1, x2, scale, out, N1, N2);
  } else {
    dim3 grid(B * N1);              // generic fallback, one row per block
    rbf_tile_kernel<1><<<grid, dim3(THREADS), 0, stream>>>(x1, x2, scale, out, N1, N2);
  }
}